// Round 10
// baseline (3673.494 us; speedup 1.0000x reference)
//
#include <hip/hip_runtime.h>
#include <math.h>

#define Bz   256
#define Tz   512
#define Sz   8
#define CD1  5
#define Hz   520
#define H4   2080
#define Ez   1024
#define Dz   1040

// persistent LSTM geometry
#define NG   16     // row groups
#define NSL  16     // j-slices per group (NG*NSL = 256 WGs)
#define RG   16     // rows per group
#define JW   34     // j per slice (16*34 = 544 >= 520)
#define NW   136    // gate columns per slice (JW*4)
#define KW   520    // K extent
#define KD   260    // dwords per K row (KW/2, bf16-packed)
#define KIT  17     // k-iterations of 32 (ceil(520/32))
#define HGD  4160   // dwords of packed h per group (RG*KW/2)
#define NTHR 512    // threads per WG (8 waves)
#define BARSTRIDE 32   // uints; 128B per flag line
#define FLGUINTS (NG * NSL * BARSTRIDE)   // 8192
#define CTRLUINTS 512

typedef float f32x4 __attribute__((ext_vector_type(4)));
typedef short s16x8 __attribute__((ext_vector_type(8)));

__device__ __forceinline__ ushort f2bf(float f) {
    uint u = __float_as_uint(f);
    uint r = (u + 0x7fffu + ((u >> 16) & 1u)) >> 16;
    return (ushort)r;
}
__device__ __forceinline__ float bf2f(ushort h) { return __uint_as_float(((uint)h) << 16); }
__device__ __forceinline__ float sigf(float v) { return 1.0f / (1.0f + expf(-v)); }

// ---- sc0 (L1-bypass, XCD-L2-served) transport helpers ----
__device__ __forceinline__ uint load_dword_sc0(const uint* p) {
    uint v;
    asm volatile("global_load_dword %0, %1, off sc0\n\ts_waitcnt vmcnt(0)"
                 : "=v"(v) : "v"(p) : "memory");
    return v;
}
__device__ __forceinline__ uint load_ushort_sc0(const ushort* p) {
    uint v;
    asm volatile("global_load_ushort %0, %1, off sc0\n\ts_waitcnt vmcnt(0)"
                 : "=v"(v) : "v"(p) : "memory");
    return v;
}
__device__ __forceinline__ void store_dword_sc0(uint* p, uint v) {
    asm volatile("global_store_dword %0, %1, off sc0" :: "v"(p), "v"(v) : "memory");
}
__device__ __forceinline__ void store_short_sc0(ushort* p, uint v) {
    asm volatile("global_store_short %0, %1, off sc0" :: "v"(p), "v"(v) : "memory");
}
// 8 strided dword loads (stride 512 dwords) via 4 bases x {0,2048B} offsets, one waitcnt
__device__ __forceinline__ void load8_sc0(const uint* b0, const uint* b1,
                                          const uint* b2, const uint* b3, uint* o) {
    asm volatile(
        "global_load_dword %0, %8, off sc0\n\t"
        "global_load_dword %1, %8, off offset:2048 sc0\n\t"
        "global_load_dword %2, %9, off sc0\n\t"
        "global_load_dword %3, %9, off offset:2048 sc0\n\t"
        "global_load_dword %4, %10, off sc0\n\t"
        "global_load_dword %5, %10, off offset:2048 sc0\n\t"
        "global_load_dword %6, %11, off sc0\n\t"
        "global_load_dword %7, %11, off offset:2048 sc0\n\t"
        "s_waitcnt vmcnt(0)"
        : "=&v"(o[0]), "=&v"(o[1]), "=&v"(o[2]), "=&v"(o[3]),
          "=&v"(o[4]), "=&v"(o[5]), "=&v"(o[6]), "=&v"(o[7])
        : "v"(b0), "v"(b1), "v"(b2), "v"(b3)
        : "memory");
}

// rank-sort rows by h_len descending (ties by index) — O(n^2), one block
__global__ void k_sort(const int* __restrict__ hl, int* __restrict__ sortedidx) {
    __shared__ int s[Bz];
    int i = threadIdx.x;
    s[i] = hl[i];
    __syncthreads();
    int mine = s[i], rank = 0;
    for (int j = 0; j < Bz; j++) {
        int o = s[j];
        rank += (o > mine) || (o == mine && j < i);
    }
    sortedidx[rank] = i;
}

// W_hh -> bf16, layout wbt[n][k]
__global__ void k_prep_w(const float* __restrict__ whh, ushort* __restrict__ wbt) {
    int idx = blockIdx.x * 256 + threadIdx.x;
    if (idx >= NW * NSL * KW) return;
    int n = idx / KW, k = idx - n * KW;
    int j = n >> 2, gate = n & 3;
    float v = (j < Hz) ? whh[(size_t)k * H4 + gate * Hz + j] : 0.0f;
    wbt[idx] = f2bf(v);
}

// permute h0_stack rows into sorted order, bf16-packed, into h buffer 1 (read at t=0)
__global__ void k_hinit(const float* __restrict__ hA, const int* __restrict__ sortedidx,
                        uint* __restrict__ h_buf1) {
    int idx = blockIdx.x * 256 + threadIdx.x;
    if (idx >= Bz * KW / 2) return;
    int rank = idx / KD, kd = idx - rank * KD;
    const float* src = hA + (size_t)sortedidx[rank] * KW + 2 * kd;
    h_buf1[idx] = (uint)f2bf(src[0]) | ((uint)f2bf(src[1]) << 16);
}

// out[m][n] = act( in[m][:] @ w[:][n] + bias[n] ), 4 rows/block
template<int K, int N, int ACT>
__global__ void k_mlp(const float* __restrict__ in, const float* __restrict__ w,
                      const float* __restrict__ bias, float* __restrict__ out) {
    int n  = blockIdx.x * 256 + threadIdx.x;
    int m0 = blockIdx.y * 4;
    if (n >= N) return;
    float acc[4];
    float bv = bias[n];
    #pragma unroll
    for (int i = 0; i < 4; i++) acc[i] = bv;
    for (int k = 0; k < K; k++) {
        float wv = w[k * N + n];
        #pragma unroll
        for (int i = 0; i < 4; i++) acc[i] += in[(m0 + i) * K + k] * wv;
    }
    #pragma unroll
    for (int i = 0; i < 4; i++) {
        float v = acc[i];
        out[(m0 + i) * N + n] = ACT ? tanhf(v) : v;
    }
}

// third encoder layer -> h-stack [x | h0], stride 520
__global__ void k_enc3(const float* __restrict__ h2, const float* __restrict__ w,
                       const float* __restrict__ bias, const float* __restrict__ x,
                       float* __restrict__ hstack) {
    int n  = blockIdx.x * 256 + threadIdx.x;
    int m0 = blockIdx.y * 4;
    float acc[4];
    float bv = bias[n];
    #pragma unroll
    for (int i = 0; i < 4; i++) acc[i] = bv;
    for (int k = 0; k < Ez; k++) {
        float wv = w[k * 512 + n];
        #pragma unroll
        for (int i = 0; i < 4; i++) acc[i] += h2[(m0 + i) * Ez + k] * wv;
    }
    #pragma unroll
    for (int i = 0; i < 4; i++) hstack[(m0 + i) * Hz + Sz + n] = acc[i];
    if (blockIdx.x == 0 && threadIdx.x < Sz) {
        #pragma unroll
        for (int i = 0; i < 4; i++)
            hstack[(m0 + i) * Hz + threadIdx.x] = x[(m0 + i) * Sz + threadIdx.x];
    }
}

// Persistent cooperative LSTM. Runtime XCD discovery: groups self-organize so all 16
// slices share an XCD; h data then moves via sc0 (shared L2). Flags: agent atomics
// (+ sc0 fast copy, monotone so dual copies are benign). Fallback: full agent path.
__global__ __launch_bounds__(NTHR, 2) void k_lstm(
        const ushort* __restrict__ wbt, const float* __restrict__ rnn_in,
        const float* __restrict__ deltas, const int* __restrict__ h_lens,
        const float* __restrict__ W_ih, const float* __restrict__ b_lstm,
        ushort* h_global, const int* __restrict__ sortedidx,
        float* __restrict__ last, unsigned int* bar) {
    __shared__ __align__(16) ushort a_lds[RG * KW];   // 16,640 B (aliased as gates fp32)
    __shared__ float c_lds[RG * JW];
    __shared__ int   rowg[RG];
    __shared__ int   hl_s[RG];
    __shared__ int   cfg[3];

    const int tid = threadIdx.x;
    unsigned int* ctrl = bar + FLGUINTS;   // [0..7]=xcdcnt [8]=ovf [9]=gridcnt [16..271]=claim

    // ---- placement discovery (one-time) ----
    if (tid == 0) {
        uint xcd;
        asm volatile("s_getreg_b32 %0, hwreg(HW_REG_XCC_ID)" : "=s"(xcd));
        xcd &= 7u;
        uint slot = __hip_atomic_fetch_add(&ctrl[xcd], 1u, __ATOMIC_RELAXED, __HIP_MEMORY_SCOPE_AGENT);
        int gg = -1, ss = 0, prim = 0;
        if (slot < 32u) {
            gg = (int)(xcd * 2u + (slot >> 4));
            ss = (int)(slot & 15u);
            prim = 1;
            __hip_atomic_store(&ctrl[16 + gg * 16 + ss], 1u, __ATOMIC_RELAXED, __HIP_MEMORY_SCOPE_AGENT);
        } else {
            ss = (int)__hip_atomic_fetch_add(&ctrl[8], 1u, __ATOMIC_RELAXED, __HIP_MEMORY_SCOPE_AGENT);
        }
        __hip_atomic_fetch_add(&ctrl[9], 1u, __ATOMIC_ACQ_REL, __HIP_MEMORY_SCOPE_AGENT);
        while (__hip_atomic_load(&ctrl[9], __ATOMIC_ACQUIRE, __HIP_MEMORY_SCOPE_AGENT) < (uint)(NG * NSL))
            __builtin_amdgcn_s_sleep(8);
        if (!prim) {   // claim the ss-th unclaimed slot
            int need = ss, found = 0;
            for (int q = 0; q < NG * NSL; q++) {
                if (__hip_atomic_load(&ctrl[16 + q], __ATOMIC_RELAXED, __HIP_MEMORY_SCOPE_AGENT) == 0u) {
                    if (need == 0) { found = q; break; }
                    need--;
                }
            }
            gg = found >> 4; ss = found & 15;
        }
        uint ownercnt = __hip_atomic_load(&ctrl[(uint)(gg >> 1)], __ATOMIC_RELAXED, __HIP_MEMORY_SCOPE_AGENT);
        cfg[0] = gg; cfg[1] = ss;
        cfg[2] = prim && (ownercnt >= ((gg & 1) ? 32u : 16u));
    }
    __syncthreads();
    const int g = cfg[0], s = cfg[1], glocal = cfg[2];

    if (tid < RG) {
        int o = sortedidx[g * RG + tid];
        rowg[tid] = o;
        hl_s[tid] = h_lens[o];
    }
    for (int idx = tid; idx < RG * JW; idx += NTHR) c_lds[idx] = 0.0f;
    __syncthreads();

    const int lane = tid & 63, wvi = tid >> 6;
    const int l15 = lane & 15, quad = lane >> 4;
    const int ntile = (wvi == 0) ? 2 : 1;
    const int tiles[2] = { wvi, 8 };

    int myrows[4];
    #pragma unroll
    for (int r = 0; r < 4; r++) myrows[r] = rowg[quad * 4 + r];
    const int gmax = hl_s[0];

    // B fragments (W_hh slice) persistent in VGPRs
    s16x8 bfrag[2][KIT];
    #pragma unroll
    for (int i = 0; i < 2; i++) {
        int nl = tiles[i] * 16 + l15;
        bool okrow = (i < ntile) && (nl < NW);
        const uint* wrow = (const uint*)wbt + (size_t)(s * NW + (nl < NW ? nl : 0)) * KD;
        #pragma unroll
        for (int kit = 0; kit < KIT; kit++) {
            s16x8 z = {0, 0, 0, 0, 0, 0, 0, 0};
            if (okrow && (kit * 32 + quad * 8 < KW))
                z = __builtin_bit_cast(s16x8, *(const uint4*)(wrow + kit * 16 + quad * 4));
            bfrag[i][kit] = z;
        }
    }

    float wihreg[2][CD1], breg[2];
    #pragma unroll
    for (int i = 0; i < 2; i++) {
        int nl = tiles[i] * 16 + l15;
        int jg = s * JW + (nl >> 2);
        bool ok = (i < ntile) && (nl < NW) && (jg < Hz);
        int col = (nl & 3) * Hz + (jg < Hz ? jg : 0);
        breg[i] = ok ? b_lstm[col] : 0.0f;
        #pragma unroll
        for (int q = 0; q < CD1; q++) wihreg[i][q] = ok ? W_ih[q * H4 + col] : 0.0f;
    }

    ushort* hbuf0 = h_global + (size_t)g * RG * KW;
    ushort* hbuf1 = h_global + (size_t)Bz * KW + (size_t)g * RG * KW;
    unsigned int* flg = bar + (size_t)(g * NSL) * BARSTRIDE;

    for (int t = 0; t < gmax; t++) {
        ushort* hw16 = (t & 1) ? hbuf1 : hbuf0;
        const ushort* hr16 = (t & 1) ? hbuf0 : hbuf1;
        const uint* hr32 = (const uint*)hr16;

        // u_t @ W_ih + b — independent of h(t-1)
        float uu[4][CD1];
        #pragma unroll
        for (int r = 0; r < 4; r++) {
            const float* up = rnn_in + ((size_t)myrows[r] * Tz + t) * CD1;
            #pragma unroll
            for (int q = 0; q < CD1; q++) uu[r][q] = up[q];
        }
        f32x4 acc[2];
        #pragma unroll
        for (int i = 0; i < 2; i++) {
            #pragma unroll
            for (int r = 0; r < 4; r++) {
                float a0 = breg[i];
                #pragma unroll
                for (int q = 0; q < CD1; q++) a0 += uu[r][q] * wihreg[i][q];
                acc[i][r] = a0;
            }
        }

        if (t > 0) {   // wait for all 16 slices: flag[s'] >= t  (sc0 fast-check, agent fallback)
            int ready;
            do {
                int ok = 1;
                if (tid < NSL) {
                    unsigned f1 = glocal ? load_dword_sc0(flg + tid * BARSTRIDE) : 0u;
                    if (f1 < (unsigned)t)
                        f1 = __hip_atomic_load(flg + tid * BARSTRIDE, __ATOMIC_ACQUIRE,
                                               __HIP_MEMORY_SCOPE_AGENT);
                    ok = f1 >= (unsigned)t;
                }
                ready = __syncthreads_and(ok);
                if (!ready) __builtin_amdgcn_s_sleep(2);
            } while (!ready);
        }

        // read group h(t-1)
        uint hpk[9];
        if (glocal) {
            const uint* b0 = hr32 + tid;
            load8_sc0(b0, b0 + 1024, b0 + 2048, b0 + 3072, hpk);
            hpk[8] = (tid + 4096 < HGD) ? load_dword_sc0(hr32 + tid + 4096) : 0u;
        } else {
            #pragma unroll
            for (int it = 0; it < 9; it++) {
                int idx = tid + it * NTHR;
                hpk[it] = (idx < HGD)
                    ? __hip_atomic_load(hr32 + idx, __ATOMIC_RELAXED, __HIP_MEMORY_SCOPE_AGENT)
                    : 0u;
            }
        }
        #pragma unroll
        for (int it = 0; it < 9; it++) {
            int idx = tid + it * NTHR;
            if (idx < HGD) ((uint*)a_lds)[idx] = hpk[it];
        }
        __syncthreads();

        // MFMA k-loop: A from LDS, B from registers
        for (int kit = 0; kit < KIT; kit++) {
            int kq = kit * 32 + quad * 8;
            s16x8 af = {0, 0, 0, 0, 0, 0, 0, 0};
            if (kq < KW)
                af = __builtin_bit_cast(s16x8,
                    *(const uint4*)((const uint*)a_lds + l15 * KD + kit * 16 + quad * 4));
            #pragma unroll
            for (int i = 0; i < 2; i++) {
                if (i >= ntile) break;
                acc[i] = __builtin_amdgcn_mfma_f32_16x16x32_bf16(af, bfrag[i][kit], acc[i], 0, 0, 0);
            }
        }
        __syncthreads();

        // gates -> LDS (aliasing a_lds)
        float* gates = (float*)a_lds;
        #pragma unroll
        for (int i = 0; i < 2; i++) {
            if (i >= ntile) break;
            int nl = tiles[i] * 16 + l15;
            if (nl < NW) {
                #pragma unroll
                for (int r = 0; r < 4; r++) gates[(quad * 4 + r) * NW + nl] = acc[i][r];
            }
        }
        __syncthreads();

        // cell update; h(t) -> write buffer; 'last' at t == hl-1
        for (int p = tid; p < RG * JW; p += NTHR) {
            int m = p / JW, jj = p - m * JW;
            int jglob = s * JW + jj;
            if (jglob < Hz && t < hl_s[m]) {
                float4 gv = *(const float4*)(gates + m * NW + jj * 4);
                float ig = sigf(gv.x), fg = sigf(gv.y), gt = tanhf(gv.z), og = sigf(gv.w);
                float cp = c_lds[p];
                float cn = fg * cp + ig * gt;
                float hn = og * tanhf(cn);
                c_lds[p] = cn;
                int hidx = m * KW + jglob;
                if (t == hl_s[m] - 1) {
                    ushort hpv = glocal
                        ? (ushort)load_ushort_sc0((const ushort*)hr16 + hidx)
                        : __hip_atomic_load((const ushort*)hr16 + hidx,
                                            __ATOMIC_RELAXED, __HIP_MEMORY_SCOPE_AGENT);
                    float hp = bf2f(hpv);
                    int orig = rowg[m];
                    float d = deltas[(size_t)orig * Tz + t];
                    last[(size_t)orig * Hz + jglob] = (1.0f - d) * hp + d * hn;
                }
                if (glocal) store_short_sc0(hw16 + hidx, (uint)f2bf(hn));
                else __hip_atomic_store(hw16 + hidx, f2bf(hn),
                                        __ATOMIC_RELAXED, __HIP_MEMORY_SCOPE_AGENT);
            }
        }

        // publish h(t): barrier drains stores (vmcnt0 per wave), then flag
        __syncthreads();
        if (tid == 0) {
            if (glocal) store_dword_sc0(flg + s * BARSTRIDE, (unsigned)(t + 1));
            __hip_atomic_store(flg + s * BARSTRIDE, (unsigned)(t + 1),
                               __ATOMIC_RELEASE, __HIP_MEMORY_SCOPE_AGENT);
        }
    }
}

// final projection: (256,1040) @ (1040,8) + bias, one block per row
__global__ void k_dec3(const float* __restrict__ z2, const float* __restrict__ w,
                       const float* __restrict__ bias, float* __restrict__ out) {
    int m = blockIdx.x, tid = threadIdx.x;
    float p[8];
    #pragma unroll
    for (int n = 0; n < 8; n++) p[n] = 0.0f;
    for (int k = tid; k < Dz; k += 256) {
        float zv = z2[(size_t)m * Dz + k];
        #pragma unroll
        for (int n = 0; n < 8; n++) p[n] += zv * w[k * 8 + n];
    }
    __shared__ float red[256][8];
    #pragma unroll
    for (int n = 0; n < 8; n++) red[tid][n] = p[n];
    __syncthreads();
    for (int s2 = 128; s2 > 0; s2 >>= 1) {
        if (tid < s2) {
            #pragma unroll
            for (int n = 0; n < 8; n++) red[tid][n] += red[tid + s2][n];
        }
        __syncthreads();
    }
    if (tid < 8) out[m * 8 + tid] = red[0][tid] + bias[tid];
}

extern "C" void kernel_launch(void* const* d_in, const int* in_sizes, int n_in,
                              void* d_out, int out_size, void* d_ws, size_t ws_size,
                              hipStream_t stream) {
    const float* x       = (const float*)d_in[0];
    const float* rnn_inp = (const float*)d_in[1];
    const float* deltas  = (const float*)d_in[2];
    const int*   h_lens  = (const int*)  d_in[3];
    const float* enc_w1  = (const float*)d_in[4];
    const float* enc_b1  = (const float*)d_in[5];
    const float* enc_w2  = (const float*)d_in[6];
    const float* enc_b2  = (const float*)d_in[7];
    const float* enc_w3  = (const float*)d_in[8];
    const float* enc_b3  = (const float*)d_in[9];
    const float* W_ih    = (const float*)d_in[10];
    const float* W_hh    = (const float*)d_in[11];
    const float* b_lstm  = (const float*)d_in[12];
    const float* dec_w1  = (const float*)d_in[13];
    const float* dec_b1  = (const float*)d_in[14];
    const float* dec_w2  = (const float*)d_in[15];
    const float* dec_b2  = (const float*)d_in[16];
    const float* dec_w3  = (const float*)d_in[17];
    const float* dec_b3  = (const float*)d_in[18];
    (void)in_sizes; (void)n_in; (void)out_size; (void)ws_size;

    char* base = (char*)d_ws;
    size_t off = 0;
    auto alloc = [&](size_t bytes) { void* p = base + off; off = (off + bytes + 255) & ~(size_t)255; return p; };
    ushort* wbt      = (ushort*)alloc((size_t)NW * NSL * KW * 2);
    ushort* h_glob   = (ushort*)alloc((size_t)2 * Bz * KW * 2);     // 2 buffers
    float*  hA       = (float*) alloc((size_t)Bz * KW * 4);
    float*  h1       = (float*) alloc((size_t)Bz * Ez * 4);
    float*  h2       = (float*) alloc((size_t)Bz * Ez * 4);
    float*  lastb    = (float*) alloc((size_t)Bz * Hz * 4);
    float*  z1       = (float*) alloc((size_t)Bz * Dz * 4);
    float*  z2       = (float*) alloc((size_t)Bz * Dz * 4);
    int*    sortedix = (int*)   alloc(Bz * 4);
    unsigned int* bar = (unsigned int*)alloc((size_t)(FLGUINTS + CTRLUINTS) * 4);
    float*  outp = (float*)d_out;

    hipMemsetAsync(bar, 0, (size_t)(FLGUINTS + CTRLUINTS) * 4, stream);
    k_sort<<<1, 256, 0, stream>>>(h_lens, sortedix);
    {
        int total = NW * NSL * KW;
        k_prep_w<<<(total + 255) / 256, 256, 0, stream>>>(W_hh, wbt);
    }

    k_mlp<Sz, Ez, 1><<<dim3(4, 64), 256, 0, stream>>>(x,  enc_w1, enc_b1, h1);
    k_mlp<Ez, Ez, 1><<<dim3(4, 64), 256, 0, stream>>>(h1, enc_w2, enc_b2, h2);
    k_enc3<<<dim3(2, 64), 256, 0, stream>>>(h2, enc_w3, enc_b3, x, hA);
    {
        int total = Bz * KW / 2;
        k_hinit<<<(total + 255) / 256, 256, 0, stream>>>(hA, sortedix,
                                                         (uint*)(h_glob + (size_t)Bz * KW));
    }

    {
        void* args[] = { (void*)&wbt, (void*)&rnn_inp, (void*)&deltas, (void*)&h_lens,
                         (void*)&W_ih, (void*)&b_lstm, (void*)&h_glob, (void*)&sortedix,
                         (void*)&lastb, (void*)&bar };
        hipLaunchCooperativeKernel(reinterpret_cast<void*>(k_lstm), dim3(NG * NSL), dim3(NTHR),
                                   args, 0, stream);
    }

    k_mlp<Hz, Dz, 1><<<dim3(5, 64), 256, 0, stream>>>(lastb, dec_w1, dec_b1, z1);
    k_mlp<Dz, Dz, 1><<<dim3(5, 64), 256, 0, stream>>>(z1,   dec_w2, dec_b2, z2);
    k_dec3<<<Bz, 256, 0, stream>>>(z2, dec_w3, dec_b3, outp);
}